// Round 3
// baseline (266.795 us; speedup 1.0000x reference)
//
#include <hip/hip_runtime.h>

// Factored single-row attention (reference returns out[:, -1, :] only).
// Per-launch precompute (kernel `precomp`, 84 blocks):
//   M2 = Wq^T Wk            [dd][d]   (so u_b = xs_b @ M2 + v0)
//   v0[d] = sum_e bq[e] Wk[e][d]
//   c[d]  = sum_e Wk[e][d]            (q-masked score path)
//   w1[dd]= sum_e bk[e] Wq[e][dd]     (q.bk = xs.w1 + bq.bk)
//   w2[dd]= sum_e Wq[e][dd]           (sum(q) = xs.w2 + sum(bq))
//   WvT   = Wv^T                      (coalesced output matvec)
//   dconst = {sum(bk), bq.bk, sum(bq)} fp64
// Main kernel (grid 256 x 256 thr, 8 batches/block):
//   stage xs49 (td-scaled) -> per-batch scalars (wave shfl dots) ->
//   phase U: u = xs@M2+v0, thread t owns d=t, acc[8], coalesced unroll-4 ->
//   attention: wave w streams batches 2w,2w+1: 4-row groups, 4-row prefetch,
//     shfl_xor dot-reduce, online softmax (fp64 scores, fp32 expf of diffs) ->
//   phase O: out = y@WvT+bv, same shape as U.
// Score paths (identical formulas to the passing rounds 1-2):
//   q-kept & s-kept : (p + q.bk)/16          (fp64)
//   q-kept & s-mask : NEG*sum(q)/16
//   q-mask & s-kept : NEG*(xs_s.c + sum(bk))/16
//   both masked     : 256e10/16 = 1.6e11

namespace {
constexpr int kB = 2048;
constexpr int kT = 50;
constexpr int kD = 256;
constexpr int kG = 8;      // batches per block
constexpr int kThr = 256;  // 4 waves
constexpr double kNeg = -100000.0;
// ws float offsets
constexpr int oM2 = 0;
constexpr int oWvT = 65536;
constexpr int oV0 = 131072;
constexpr int oC = 131328;
constexpr int oW1 = 131584;
constexpr int oW2 = 131840;
constexpr int oDbl = 132096;  // 3 doubles at byte offset 528384 (8-aligned)
}  // namespace

__global__ __launch_bounds__(kThr) void precomp(
    const float* __restrict__ Wq, const float* __restrict__ bq,
    const float* __restrict__ Wk, const float* __restrict__ bk,
    const float* __restrict__ Wv, float* __restrict__ ws) {
  float* M2 = ws + oM2;
  float* WvT = ws + oWvT;
  double* dconst = (double*)(ws + oDbl);
  const int t = threadIdx.x;
  const int blk = blockIdx.x;
  __shared__ float tile[64][65];
  __shared__ double red[3][4];

  if (blk < 64) {
    // M2 rows a0..a0+3:  M2[a][d] = sum_e Wq[e][a] * Wk[e][d], d = t
    const int a0 = blk * 4;
    float acc0 = 0.f, acc1 = 0.f, acc2 = 0.f, acc3 = 0.f;
    for (int e = 0; e < kD; e += 4) {
#pragma unroll
      for (int i = 0; i < 4; ++i) {
        const float wk = Wk[(size_t)(e + i) * kD + t];
        const float4 wq = *(const float4*)(Wq + (size_t)(e + i) * kD + a0);
        acc0 += wq.x * wk;
        acc1 += wq.y * wk;
        acc2 += wq.z * wk;
        acc3 += wq.w * wk;
      }
    }
    M2[(size_t)(a0 + 0) * kD + t] = acc0;
    M2[(size_t)(a0 + 1) * kD + t] = acc1;
    M2[(size_t)(a0 + 2) * kD + t] = acc2;
    M2[(size_t)(a0 + 3) * kD + t] = acc3;
  } else if (blk < 68) {
    // coeff-weighted column sums: dst[d] = sum_e coef[e] * W[e][d]
    const float* W = (blk < 66) ? Wk : Wq;
    const float* coef = (blk == 64) ? bq : (blk == 66) ? bk : nullptr;
    double acc = 0.0;
    for (int e = 0; e < kD; e += 4) {
#pragma unroll
      for (int i = 0; i < 4; ++i) {
        const double w = (double)W[(size_t)(e + i) * kD + t];
        acc += coef ? (double)coef[e + i] * w : w;
      }
    }
    float* dst = (blk == 64)   ? ws + oV0
                 : (blk == 65) ? ws + oC
                 : (blk == 66) ? ws + oW1
                               : ws + oW2;
    dst[t] = (float)acc;
    if (blk == 65) {
      // dconst = {sum(bk), bq.bk, sum(bq)}
      double p0 = (double)bk[t];
      double p1 = (double)bq[t] * (double)bk[t];
      double p2 = (double)bq[t];
      const int lane = t & 63, wv = t >> 6;
#pragma unroll
      for (int off = 32; off; off >>= 1) {
        p0 += __shfl_xor(p0, off);
        p1 += __shfl_xor(p1, off);
        p2 += __shfl_xor(p2, off);
      }
      if (lane == 0) {
        red[0][wv] = p0;
        red[1][wv] = p1;
        red[2][wv] = p2;
      }
      __syncthreads();
      if (t == 0) {
        dconst[0] = red[0][0] + red[0][1] + red[0][2] + red[0][3];
        dconst[1] = red[1][0] + red[1][1] + red[1][2] + red[1][3];
        dconst[2] = red[2][0] + red[2][1] + red[2][2] + red[2][3];
      }
    }
  } else {
    // transpose Wv 64x64 tile -> WvT
    const int tb = blk - 68;
    const int tr = tb >> 2, tc = tb & 3;
    const int j = t & 63;
#pragma unroll 4
    for (int p = 0; p < 16; ++p) {
      const int i = p * 4 + (t >> 6);
      tile[i][j] = Wv[(size_t)(tr * 64 + i) * kD + tc * 64 + j];
    }
    __syncthreads();
#pragma unroll 4
    for (int p = 0; p < 16; ++p) {
      const int r = p * 4 + (t >> 6);
      WvT[(size_t)(tc * 64 + r) * kD + tr * 64 + j] = tile[j][r];
    }
  }
}

__global__ __launch_bounds__(kThr) void attn_main(
    const float* __restrict__ x, const int* __restrict__ mask,
    const float* __restrict__ td, const float* __restrict__ bv,
    const float* __restrict__ ws, float* __restrict__ out) {
  const float* M2 = ws + oM2;
  const float* WvT = ws + oWvT;
  const float* v0 = ws + oV0;
  const float* cv = ws + oC;
  const float* w1 = ws + oW1;
  const float* w2 = ws + oW2;
  const double* dconst = (const double*)(ws + oDbl);

  __shared__ __align__(16) float xs[kG][kD];  // 8 KB
  __shared__ __align__(16) float ub[kG][kD];  // 8 KB
  __shared__ __align__(16) float yb[kG][kD];  // 8 KB
  __shared__ float tdb[kG * kT];
  __shared__ int mb[kG * kT];
  __shared__ double Sqb[kG], Qbkb[kG];

  const int t = threadIdx.x;
  const int wave = t >> 6;
  const int lane = t & 63;
  const int b0 = blockIdx.x * kG;

  // ---- stage td/mask (400 contiguous) and xs49 (td-scaled) ----
  for (int idx = t; idx < kG * kT; idx += kThr) {
    tdb[idx] = td[b0 * kT + idx];
    mb[idx] = mask[b0 * kT + idx];
  }
  for (int idx = t; idx < kG * 64; idx += kThr) {
    const int g = idx >> 6, c4 = idx & 63;
    const float tv = td[(b0 + g) * kT + (kT - 1)];
    float4 xv =
        ((const float4*)(x + ((size_t)(b0 + g) * kT + kT - 1) * kD))[c4];
    xv.x *= tv; xv.y *= tv; xv.z *= tv; xv.w *= tv;
    ((float4*)(&xs[g][0]))[c4] = xv;
  }
  __syncthreads();

  // ---- per-batch scalars: wave w -> batches 2w, 2w+1 ----
#pragma unroll
  for (int gb = 0; gb < 2; ++gb) {
    const int g = wave * 2 + gb;
    const float4 xv = ((const float4*)(&xs[g][0]))[lane];
    const float4 a1 = ((const float4*)w1)[lane];
    const float4 a2 = ((const float4*)w2)[lane];
    double s1 = (double)xv.x * a1.x + (double)xv.y * a1.y +
                (double)xv.z * a1.z + (double)xv.w * a1.w;
    double s2 = (double)xv.x * a2.x + (double)xv.y * a2.y +
                (double)xv.z * a2.z + (double)xv.w * a2.w;
#pragma unroll
    for (int off = 32; off; off >>= 1) {
      s1 += __shfl_xor(s1, off);
      s2 += __shfl_xor(s2, off);
    }
    if (lane == 0) {
      Qbkb[g] = s1 + dconst[1];
      Sqb[g] = s2 + dconst[2];
    }
  }

  // ---- phase U: u[g][t] = sum_dd xs[g][dd] * M2[dd][t] + v0[t] ----
  {
    float acc[kG];
    const float v0t = v0[t];
#pragma unroll
    for (int j = 0; j < kG; ++j) acc[j] = v0t;
    for (int dd = 0; dd < kD; dd += 4) {
      const float m0 = M2[(size_t)(dd + 0) * kD + t];
      const float m1 = M2[(size_t)(dd + 1) * kD + t];
      const float m2 = M2[(size_t)(dd + 2) * kD + t];
      const float m3 = M2[(size_t)(dd + 3) * kD + t];
#pragma unroll
      for (int j = 0; j < kG; ++j) {
        const float4 xj = *(const float4*)(&xs[j][dd]);
        acc[j] += xj.x * m0 + xj.y * m1 + xj.z * m2 + xj.w * m3;
      }
    }
#pragma unroll
    for (int j = 0; j < kG; ++j) ub[j][t] = acc[j];
  }
  __syncthreads();

  // ---- attention: wave w streams batches 2w, 2w+1 (no barriers) ----
  const double sbkd = dconst[0];
  const double Cbb = 256.0 * 1.0e10 * 0.0625;  // both-masked const
  for (int gb = 0; gb < 2; ++gb) {
    const int g = wave * 2 + gb;
    const int b = b0 + g;
    const int base = g * kT;
    const float4* xrow = (const float4*)(x + (size_t)b * kT * kD);
    const float4 u4 = ((const float4*)(&ub[g][0]))[lane];
    const float4 c4 = ((const float4*)cv)[lane];
    const int mqg = mb[base + (kT - 1)];
    const float4 v4 = mqg ? u4 : c4;
    const double Cm = kNeg * Sqb[g] * 0.0625;  // q kept, s masked
    const double Qbk = Qbkb[g];

    double m = -1.0e300;
    float l = 0.f;
    float4 y = {0.f, 0.f, 0.f, 0.f};

    float4 n0 = xrow[0 * 64 + lane];
    float4 n1 = xrow[1 * 64 + lane];
    float4 n2 = xrow[2 * 64 + lane];
    float4 n3 = xrow[3 * 64 + lane];
    for (int s = 0; s < 52; s += 4) {
      const float4 r0 = n0, r1 = n1, r2 = n2, r3 = n3;
      // prefetch next group (clamped; redundant loads past end are harmless)
      {
        const int p0 = (s + 4 < kT) ? s + 4 : kT - 1;
        const int p1 = (s + 5 < kT) ? s + 5 : kT - 1;
        const int p2 = (s + 6 < kT) ? s + 6 : kT - 1;
        const int p3 = (s + 7 < kT) ? s + 7 : kT - 1;
        n0 = xrow[p0 * 64 + lane];
        n1 = xrow[p1 * 64 + lane];
        n2 = xrow[p2 * 64 + lane];
        n3 = xrow[p3 * 64 + lane];
      }
      const int s0i = s, s1i = s + 1, s2i = s + 2, s3i = s + 3;
      const int c0 = (s0i < kT) ? s0i : kT - 1;
      const int c1 = (s1i < kT) ? s1i : kT - 1;
      const int c2 = (s2i < kT) ? s2i : kT - 1;
      const int c3 = (s3i < kT) ? s3i : kT - 1;
      const float tv0 = tdb[base + c0];
      const float tv1 = tdb[base + c1];
      const float tv2 = tdb[base + c2];
      const float tv3 = tdb[base + c3];
      float4 a0, a1, a2, a3;
      a0.x = r0.x * tv0; a0.y = r0.y * tv0; a0.z = r0.z * tv0; a0.w = r0.w * tv0;
      a1.x = r1.x * tv1; a1.y = r1.y * tv1; a1.z = r1.z * tv1; a1.w = r1.w * tv1;
      a2.x = r2.x * tv2; a2.y = r2.y * tv2; a2.z = r2.z * tv2; a2.w = r2.w * tv2;
      a3.x = r3.x * tv3; a3.y = r3.y * tv3; a3.z = r3.z * tv3; a3.w = r3.w * tv3;
      float p0 = a0.x * v4.x + a0.y * v4.y + a0.z * v4.z + a0.w * v4.w;
      float p1 = a1.x * v4.x + a1.y * v4.y + a1.z * v4.z + a1.w * v4.w;
      float p2 = a2.x * v4.x + a2.y * v4.y + a2.z * v4.z + a2.w * v4.w;
      float p3 = a3.x * v4.x + a3.y * v4.y + a3.z * v4.z + a3.w * v4.w;
#pragma unroll
      for (int off = 32; off; off >>= 1) {
        p0 += __shfl_xor(p0, off);
        p1 += __shfl_xor(p1, off);
        p2 += __shfl_xor(p2, off);
        p3 += __shfl_xor(p3, off);
      }
      const int ms0 = mb[base + c0];
      const int ms1 = mb[base + c1];
      const int ms2 = mb[base + c2];
      const int ms3 = mb[base + c3];
      double sc0, sc1, sc2, sc3;
      if (mqg) {
        sc0 = ms0 ? ((double)p0 + Qbk) * 0.0625 : Cm;
        sc1 = ms1 ? ((double)p1 + Qbk) * 0.0625 : Cm;
        sc2 = ms2 ? ((double)p2 + Qbk) * 0.0625 : Cm;
        sc3 = ms3 ? ((double)p3 + Qbk) * 0.0625 : Cm;
      } else {
        sc0 = ms0 ? kNeg * ((double)p0 + sbkd) * 0.0625 : Cbb;
        sc1 = ms1 ? kNeg * ((double)p1 + sbkd) * 0.0625 : Cbb;
        sc2 = ms2 ? kNeg * ((double)p2 + sbkd) * 0.0625 : Cbb;
        sc3 = ms3 ? kNeg * ((double)p3 + sbkd) * 0.0625 : Cbb;
      }
      if (s1i >= kT) sc1 = -1.0e300;
      if (s2i >= kT) sc2 = -1.0e300;
      if (s3i >= kT) sc3 = -1.0e300;
      double mnew = m;
      if (sc0 > mnew) mnew = sc0;
      if (sc1 > mnew) mnew = sc1;
      if (sc2 > mnew) mnew = sc2;
      if (sc3 > mnew) mnew = sc3;
      const float al = expf((float)(m - mnew));
      const float e0 = expf((float)(sc0 - mnew));
      const float e1 = expf((float)(sc1 - mnew));
      const float e2 = expf((float)(sc2 - mnew));
      const float e3 = expf((float)(sc3 - mnew));
      m = mnew;
      l = l * al + e0 + e1 + e2 + e3;
      y.x = y.x * al + e0 * a0.x + e1 * a1.x + e2 * a2.x + e3 * a3.x;
      y.y = y.y * al + e0 * a0.y + e1 * a1.y + e2 * a2.y + e3 * a3.y;
      y.z = y.z * al + e0 * a0.z + e1 * a1.z + e2 * a2.z + e3 * a3.z;
      y.w = y.w * al + e0 * a0.w + e1 * a1.w + e2 * a2.w + e3 * a3.w;
    }
    const float inv = 1.0f / l;
    y.x *= inv; y.y *= inv; y.z *= inv; y.w *= inv;
    ((float4*)(&yb[g][0]))[lane] = y;
  }
  __syncthreads();

  // ---- phase O: out[b0+j][t] = sum_d yb[j][d] * WvT[d][t] + bv[t] ----
  {
    float acc[kG];
    const float bvt = bv[t];
#pragma unroll
    for (int j = 0; j < kG; ++j) acc[j] = bvt;
    for (int dd = 0; dd < kD; dd += 4) {
      const float m0 = WvT[(size_t)(dd + 0) * kD + t];
      const float m1 = WvT[(size_t)(dd + 1) * kD + t];
      const float m2 = WvT[(size_t)(dd + 2) * kD + t];
      const float m3 = WvT[(size_t)(dd + 3) * kD + t];
#pragma unroll
      for (int j = 0; j < kG; ++j) {
        const float4 yj = *(const float4*)(&yb[j][dd]);
        acc[j] += yj.x * m0 + yj.y * m1 + yj.z * m2 + yj.w * m3;
      }
    }
#pragma unroll
    for (int j = 0; j < kG; ++j) out[(size_t)(b0 + j) * kD + t] = acc[j];
  }
}

extern "C" void kernel_launch(void* const* d_in, const int* in_sizes, int n_in,
                              void* d_out, int out_size, void* d_ws,
                              size_t ws_size, hipStream_t stream) {
  const float* x = (const float*)d_in[0];
  const int* mask = (const int*)d_in[1];
  const float* td = (const float*)d_in[2];
  const float* Wq = (const float*)d_in[3];
  const float* bq = (const float*)d_in[4];
  const float* Wk = (const float*)d_in[5];
  const float* bk = (const float*)d_in[6];
  const float* Wv = (const float*)d_in[7];
  const float* bv = (const float*)d_in[8];
  float* ws = (float*)d_ws;  // needs ~517 KB
  float* out = (float*)d_out;
  (void)in_sizes; (void)n_in; (void)out_size; (void)ws_size;

  hipLaunchKernelGGL(precomp, dim3(84), dim3(kThr), 0, stream, Wq, bq, Wk, bk,
                     Wv, ws);
  hipLaunchKernelGGL(attn_main, dim3(kB / kG), dim3(kThr), 0, stream, x, mask,
                     td, bv, (const float*)ws, out);
}

// Round 5
// 224.472 us; speedup vs baseline: 1.1885x; 1.1885x over previous
//
#include <hip/hip_runtime.h>

// Factored single-row attention (reference returns out[:, -1, :] only).
// ws layout (floats): M2p [0,65536) packed [dd4][t][4]; Wvp [65536,131072)
// packed [d4][t][4]; v0 @131072; c @131328; w1 @131584; w2 @131840;
// dconst (3 doubles) @132096.
//   M2[f][d] = sum_e Wq[e][f] Wk[e][d]  (u = xs@M2 + v0)
//   v0[d] = sum_e bq[e] Wk[e][d];  c[d] = sum_e Wk[e][d]
//   w1[f] = sum_e bk[e] Wq[e][f];  w2[f] = sum_e Wq[e][f]
//   dconst = {sum(bk), bq.bk, sum(bq)}
// Score paths (identical to passing rounds 1-3):
//   q-kept & s-kept : (xs_s.u + q.bk)/16   q-kept & s-mask: NEG*sum(q)/16
//   q-mask & s-kept : NEG*(xs_s.c + sum(bk))/16   both: 1.6e11
// precomp (274 blocks): M2 row-per-block; EACH THREAD walks the FULL
// 256-e range for its own column (round-4 bug: wave-split covered only
// 1/4 of (e,d) pairs -> uninitialized LDS -> NaN). 8-deep register
// prefetch keeps 8 loads in flight (round-3 fix for VGPR=16 serial chains).
// attn_main: grid 512 x 256thr, 4 batches/block; U/O phases use packed
// float4 weight loads + 8-deep prefetch; attention is one wave per batch,
// zero barriers, online softmax (fp64 scores, fp32 expf of differences).

namespace {
constexpr int kB = 2048;
constexpr int kT = 50;
constexpr int kD = 256;
constexpr int kG = 4;
constexpr int kThr = 256;
constexpr double kNeg = -100000.0;
constexpr int oM2 = 0;
constexpr int oWvp = 65536;
constexpr int oV0 = 131072;
constexpr int oC = 131328;
constexpr int oW1 = 131584;
constexpr int oW2 = 131840;
constexpr int oDbl = 132096;
}  // namespace

__global__ __launch_bounds__(kThr) void precomp(
    const float* __restrict__ Wq, const float* __restrict__ bq,
    const float* __restrict__ Wk, const float* __restrict__ bk,
    const float* __restrict__ Wv, float* __restrict__ ws) {
  const int t = threadIdx.x;
  const int wave = t >> 6;
  const int lane = t & 63;
  const int blk = blockIdx.x;
  __shared__ float coefL[kD];
  __shared__ double red[3][4];

  if (blk < 256) {
    // M2 row a: M2[a][d] = sum_e Wq[e][a] * Wk[e][d]; thread t -> col d=t,
    // full e range, 8-deep rotating prefetch.
    const int a = blk;
    coefL[t] = Wq[(size_t)t * kD + a];  // column-a gather of Wq
    __syncthreads();
    const float* kcol = Wk + t;
    float pre[8];
#pragma unroll
    for (int k = 0; k < 8; ++k) pre[k] = kcol[(size_t)k * kD];
    float acc = 0.f;
    for (int j0 = 0; j0 < kD; j0 += 8) {
      float cur[8];
#pragma unroll
      for (int k = 0; k < 8; ++k) cur[k] = pre[k];
      const int nx = (j0 + 8 < kD) ? (j0 + 8) : 0;  // wrap: harmless
#pragma unroll
      for (int k = 0; k < 8; ++k) pre[k] = kcol[(size_t)(nx + k) * kD];
#pragma unroll
      for (int k = 0; k < 8; ++k) acc += coefL[j0 + k] * cur[k];
    }
    ws[oM2 + (a >> 2) * 1024 + 4 * t + (a & 3)] = acc;  // packed [dd4][t][4]
  } else if (blk < 258) {
    // fused column sums over full e range:
    //   blk 256 -> {v0 (coef=bq), c} over Wk; blk 257 -> {w1 (coef=bk), w2} over Wq
    const float* W = (blk == 256) ? Wk : Wq;
    const float* coef = (blk == 256) ? bq : bk;
    coefL[t] = coef[t];
    __syncthreads();
    const float* col = W + t;
    float pre[8];
#pragma unroll
    for (int k = 0; k < 8; ++k) pre[k] = col[(size_t)k * kD];
    double a0 = 0.0, a1 = 0.0;
    for (int j0 = 0; j0 < kD; j0 += 8) {
      float cur[8];
#pragma unroll
      for (int k = 0; k < 8; ++k) cur[k] = pre[k];
      const int nx = (j0 + 8 < kD) ? (j0 + 8) : 0;
#pragma unroll
      for (int k = 0; k < 8; ++k) pre[k] = col[(size_t)(nx + k) * kD];
#pragma unroll
      for (int k = 0; k < 8; ++k) {
        const double w = (double)cur[k];
        a0 += (double)coefL[j0 + k] * w;
        a1 += w;
      }
    }
    if (blk == 256) {
      ws[oV0 + t] = (float)a0;
      ws[oC + t] = (float)a1;
    } else {
      ws[oW1 + t] = (float)a0;
      ws[oW2 + t] = (float)a1;
      // dconst = {sum(bk), bq.bk, sum(bq)} — 4-wave shfl reduce (correct:
      // each thread contributes its own t; 4 waves cover all 256).
      double p0 = (double)bk[t];
      double p1 = (double)bq[t] * (double)bk[t];
      double p2 = (double)bq[t];
#pragma unroll
      for (int off = 32; off; off >>= 1) {
        p0 += __shfl_xor(p0, off);
        p1 += __shfl_xor(p1, off);
        p2 += __shfl_xor(p2, off);
      }
      if (lane == 0) {
        red[0][wave] = p0;
        red[1][wave] = p1;
        red[2][wave] = p2;
      }
      __syncthreads();
      if (t == 0) {
        double* dc = (double*)(ws + oDbl);
        dc[0] = red[0][0] + red[0][1] + red[0][2] + red[0][3];
        dc[1] = red[1][0] + red[1][1] + red[1][2] + red[1][3];
        dc[2] = red[2][0] + red[2][1] + red[2][2] + red[2][3];
      }
    }
  } else {
    // Wv pack: Wvp[d4][t][0..3] = Wv[t][4*d4 .. 4*d4+3]
    const int d4b = (blk - 258) * 4;
    float4 in[4];
#pragma unroll
    for (int k = 0; k < 4; ++k)
      in[k] = *(const float4*)(Wv + (size_t)t * kD + 4 * (d4b + k));
    float4* Wvp = (float4*)(ws + oWvp);
#pragma unroll
    for (int k = 0; k < 4; ++k) Wvp[(size_t)(d4b + k) * kD + t] = in[k];
  }
}

__global__ __launch_bounds__(kThr, 2) void attn_main(
    const float* __restrict__ x, const int* __restrict__ mask,
    const float* __restrict__ td, const float* __restrict__ bv,
    const float* __restrict__ ws, float* __restrict__ out) {
  const float4* M2v = (const float4*)(ws + oM2);   // [dd4*256 + t]
  const float4* Wvv = (const float4*)(ws + oWvp);  // [d4*256 + t]
  const float* v0 = ws + oV0;
  const float* cv = ws + oC;
  const double* dconst = (const double*)(ws + oDbl);

  __shared__ __align__(16) float4 xsf[kG][kD / 4];  // 4 KB
  __shared__ __align__(16) float ub[kG][kD];        // 4 KB
  __shared__ __align__(16) float4 ybf[kG][kD / 4];  // 4 KB
  __shared__ float tdb[kG * kT];
  __shared__ int mb[kG * kT];
  __shared__ double Sqb[kG], Qbkb[kG];

  const int t = threadIdx.x;
  const int wave = t >> 6;
  const int lane = t & 63;
  const int b0 = blockIdx.x * kG;

  // ---- stage td/mask + xs49 (td-scaled, wave g -> batch g) ----
  if (t < kG * kT) {
    tdb[t] = td[b0 * kT + t];
    mb[t] = mask[b0 * kT + t];
  }
  {
    const int g = wave;
    const float tv = td[(b0 + g) * kT + (kT - 1)];
    float4 xv =
        ((const float4*)(x + ((size_t)(b0 + g) * kT + kT - 1) * kD))[lane];
    xv.x *= tv; xv.y *= tv; xv.z *= tv; xv.w *= tv;
    xsf[g][lane] = xv;
  }
  __syncthreads();

  // ---- per-batch scalars (wave g -> batch g) ----
  {
    const int g = wave;
    const float4 xv = xsf[g][lane];
    const float4 a1 = ((const float4*)(ws + oW1))[lane];
    const float4 a2 = ((const float4*)(ws + oW2))[lane];
    double s1 = (double)xv.x * a1.x + (double)xv.y * a1.y +
                (double)xv.z * a1.z + (double)xv.w * a1.w;
    double s2 = (double)xv.x * a2.x + (double)xv.y * a2.y +
                (double)xv.z * a2.z + (double)xv.w * a2.w;
#pragma unroll
    for (int off = 32; off; off >>= 1) {
      s1 += __shfl_xor(s1, off);
      s2 += __shfl_xor(s2, off);
    }
    if (lane == 0) {
      Qbkb[g] = s1 + dconst[1];
      Sqb[g] = s2 + dconst[2];
    }
  }

  // ---- phase U: u[j][t] = sum_dd4 dot(xs[j][dd4], M2p[dd4][t]) + v0[t] ----
  {
    float4 pre[8];
#pragma unroll
    for (int k = 0; k < 8; ++k) pre[k] = M2v[(size_t)k * kD + t];
    float acc[kG];
    const float v0t = v0[t];
#pragma unroll
    for (int j = 0; j < kG; ++j) acc[j] = v0t;
    for (int j0 = 0; j0 < 64; j0 += 8) {
      float4 cur[8];
#pragma unroll
      for (int k = 0; k < 8; ++k) cur[k] = pre[k];
      const int nx = (j0 + 8 < 64) ? (j0 + 8) : 0;  // wrap: harmless
#pragma unroll
      for (int k = 0; k < 8; ++k) pre[k] = M2v[(size_t)(nx + k) * kD + t];
#pragma unroll
      for (int k = 0; k < 8; ++k) {
#pragma unroll
        for (int j = 0; j < kG; ++j) {
          const float4 xj = xsf[j][j0 + k];
          acc[j] += xj.x * cur[k].x + xj.y * cur[k].y + xj.z * cur[k].z +
                    xj.w * cur[k].w;
        }
      }
    }
#pragma unroll
    for (int j = 0; j < kG; ++j) ub[j][t] = acc[j];
  }
  __syncthreads();

  // ---- attention: wave g streams batch b0+g, zero barriers ----
  {
    const int g = wave;
    const int b = b0 + g;
    const int base = g * kT;
    const float4* xrow = (const float4*)(x + (size_t)b * kT * kD);
    const float4 u4 = ((const float4*)(&ub[g][0]))[lane];
    const float4 c4 = ((const float4*)cv)[lane];
    const int mqg = mb[base + (kT - 1)];
    const float4 v4 = mqg ? u4 : c4;
    const double Cm = kNeg * Sqb[g] * 0.0625;
    const double Cbb = 256.0 * 1.0e10 * 0.0625;
    const double Qbk = Qbkb[g];
    const double sbkd = dconst[0];

    double m = -1.0e300;
    float l = 0.f;
    float4 y = {0.f, 0.f, 0.f, 0.f};

    float4 n0 = xrow[0 * 64 + lane];
    float4 n1 = xrow[1 * 64 + lane];
    float4 n2 = xrow[2 * 64 + lane];
    float4 n3 = xrow[3 * 64 + lane];
    for (int s = 0; s < 52; s += 4) {
      const float4 r0 = n0, r1 = n1, r2 = n2, r3 = n3;
      {
        const int p0 = (s + 4 < kT) ? s + 4 : kT - 1;
        const int p1 = (s + 5 < kT) ? s + 5 : kT - 1;
        const int p2 = (s + 6 < kT) ? s + 6 : kT - 1;
        const int p3 = (s + 7 < kT) ? s + 7 : kT - 1;
        n0 = xrow[p0 * 64 + lane];
        n1 = xrow[p1 * 64 + lane];
        n2 = xrow[p2 * 64 + lane];
        n3 = xrow[p3 * 64 + lane];
      }
      const int s1i = s + 1, s2i = s + 2, s3i = s + 3;
      const int c0 = s;
      const int c1 = (s1i < kT) ? s1i : kT - 1;
      const int c2 = (s2i < kT) ? s2i : kT - 1;
      const int c3 = (s3i < kT) ? s3i : kT - 1;
      const float tv0 = tdb[base + c0];
      const float tv1 = tdb[base + c1];
      const float tv2 = tdb[base + c2];
      const float tv3 = tdb[base + c3];
      float4 a0, a1, a2, a3;
      a0.x = r0.x * tv0; a0.y = r0.y * tv0; a0.z = r0.z * tv0; a0.w = r0.w * tv0;
      a1.x = r1.x * tv1; a1.y = r1.y * tv1; a1.z = r1.z * tv1; a1.w = r1.w * tv1;
      a2.x = r2.x * tv2; a2.y = r2.y * tv2; a2.z = r2.z * tv2; a2.w = r2.w * tv2;
      a3.x = r3.x * tv3; a3.y = r3.y * tv3; a3.z = r3.z * tv3; a3.w = r3.w * tv3;
      float p0 = a0.x * v4.x + a0.y * v4.y + a0.z * v4.z + a0.w * v4.w;
      float p1 = a1.x * v4.x + a1.y * v4.y + a1.z * v4.z + a1.w * v4.w;
      float p2 = a2.x * v4.x + a2.y * v4.y + a2.z * v4.z + a2.w * v4.w;
      float p3 = a3.x * v4.x + a3.y * v4.y + a3.z * v4.z + a3.w * v4.w;
#pragma unroll
      for (int off = 32; off; off >>= 1) {
        p0 += __shfl_xor(p0, off);
        p1 += __shfl_xor(p1, off);
        p2 += __shfl_xor(p2, off);
        p3 += __shfl_xor(p3, off);
      }
      const int ms0 = mb[base + c0];
      const int ms1 = mb[base + c1];
      const int ms2 = mb[base + c2];
      const int ms3 = mb[base + c3];
      double sc0, sc1, sc2, sc3;
      if (mqg) {
        sc0 = ms0 ? ((double)p0 + Qbk) * 0.0625 : Cm;
        sc1 = ms1 ? ((double)p1 + Qbk) * 0.0625 : Cm;
        sc2 = ms2 ? ((double)p2 + Qbk) * 0.0625 : Cm;
        sc3 = ms3 ? ((double)p3 + Qbk) * 0.0625 : Cm;
      } else {
        sc0 = ms0 ? kNeg * ((double)p0 + sbkd) * 0.0625 : Cbb;
        sc1 = ms1 ? kNeg * ((double)p1 + sbkd) * 0.0625 : Cbb;
        sc2 = ms2 ? kNeg * ((double)p2 + sbkd) * 0.0625 : Cbb;
        sc3 = ms3 ? kNeg * ((double)p3 + sbkd) * 0.0625 : Cbb;
      }
      if (s1i >= kT) sc1 = -1.0e300;
      if (s2i >= kT) sc2 = -1.0e300;
      if (s3i >= kT) sc3 = -1.0e300;
      double mnew = m;
      if (sc0 > mnew) mnew = sc0;
      if (sc1 > mnew) mnew = sc1;
      if (sc2 > mnew) mnew = sc2;
      if (sc3 > mnew) mnew = sc3;
      const float al = expf((float)(m - mnew));
      const float e0 = expf((float)(sc0 - mnew));
      const float e1 = expf((float)(sc1 - mnew));
      const float e2 = expf((float)(sc2 - mnew));
      const float e3 = expf((float)(sc3 - mnew));
      m = mnew;
      l = l * al + e0 + e1 + e2 + e3;
      y.x = y.x * al + e0 * a0.x + e1 * a1.x + e2 * a2.x + e3 * a3.x;
      y.y = y.y * al + e0 * a0.y + e1 * a1.y + e2 * a2.y + e3 * a3.y;
      y.z = y.z * al + e0 * a0.z + e1 * a1.z + e2 * a2.z + e3 * a3.z;
      y.w = y.w * al + e0 * a0.w + e1 * a1.w + e2 * a2.w + e3 * a3.w;
    }
    const float inv = 1.0f / l;
    y.x *= inv; y.y *= inv; y.z *= inv; y.w *= inv;
    ybf[g][lane] = y;
  }
  __syncthreads();

  // ---- phase O: out[b0+j][t] = sum_d4 dot(y[j][d4], Wvp[d4][t]) + bv[t] ----
  {
    float4 pre[8];
#pragma unroll
    for (int k = 0; k < 8; ++k) pre[k] = Wvv[(size_t)k * kD + t];
    float acc[kG];
    const float bvt = bv[t];
#pragma unroll
    for (int j = 0; j < kG; ++j) acc[j] = bvt;
    for (int j0 = 0; j0 < 64; j0 += 8) {
      float4 cur[8];
#pragma unroll
      for (int k = 0; k < 8; ++k) cur[k] = pre[k];
      const int nx = (j0 + 8 < 64) ? (j0 + 8) : 0;
#pragma unroll
      for (int k = 0; k < 8; ++k) pre[k] = Wvv[(size_t)(nx + k) * kD + t];
#pragma unroll
      for (int k = 0; k < 8; ++k) {
#pragma unroll
        for (int j = 0; j < kG; ++j) {
          const float4 yj = ybf[j][j0 + k];
          acc[j] += yj.x * cur[k].x + yj.y * cur[k].y + yj.z * cur[k].z +
                    yj.w * cur[k].w;
        }
      }
    }
#pragma unroll
    for (int j = 0; j < kG; ++j) out[(size_t)(b0 + j) * kD + t] = acc[j];
  }
}

extern "C" void kernel_launch(void* const* d_in, const int* in_sizes, int n_in,
                              void* d_out, int out_size, void* d_ws,
                              size_t ws_size, hipStream_t stream) {
  const float* x = (const float*)d_in[0];
  const int* mask = (const int*)d_in[1];
  const float* td = (const float*)d_in[2];
  const float* Wq = (const float*)d_in[3];
  const float* bq = (const float*)d_in[4];
  const float* Wk = (const float*)d_in[5];
  const float* bk = (const float*)d_in[6];
  const float* Wv = (const float*)d_in[7];
  const float* bv = (const float*)d_in[8];
  float* ws = (float*)d_ws;
  float* out = (float*)d_out;
  (void)in_sizes; (void)n_in; (void)out_size; (void)ws_size;

  hipLaunchKernelGGL(precomp, dim3(274), dim3(kThr), 0, stream, Wq, bq, Wk, bk,
                     Wv, ws);
  hipLaunchKernelGGL(attn_main, dim3(kB / kG), dim3(kThr), 0, stream, x, mask,
                     td, bv, (const float*)ws, out);
}